// Round 1
// baseline (143.756 us; speedup 1.0000x reference)
//
#include <hip/hip_runtime.h>
#include <hip/hip_bf16.h>

#define BATCH 64
#define SEQ 32
#define DIM 1024
#define EOUT 4096
#define NFW 16

#define BM 128   // rows per block tile (4 batch-slots x 32 seq)
#define BN 128   // cols per block tile
#define BK 64    // k chunk
#define LDS_K 68 // padded row stride in bf16 elements (136B -> b64 reads 2-way only)

typedef float  f32x4 __attribute__((ext_vector_type(4)));
typedef short  s16x4 __attribute__((ext_vector_type(4)));
typedef short  s16x8 __attribute__((ext_vector_type(8)));

__device__ __forceinline__ short f2bf(float f) {
    union { float f; unsigned u; } v; v.f = f;
    unsigned r = v.u + 0x7fffu + ((v.u >> 16) & 1u);   // RNE
    return (short)(r >> 16);
}

__global__ __launch_bounds__(256) void qgen_kernel(
    const float* __restrict__ x,      // [64][32][1024]
    const int*   __restrict__ fwv,    // [64]
    const float* __restrict__ w,      // [16][1024][4096]
    const float* __restrict__ bias,   // [16][4096]
    float*       __restrict__ out)    // [64][32][4096] flat
{
    const int tid   = threadIdx.x;
    const int ntile = blockIdx.x;
    const int mg    = blockIdx.y;
    const int myfw  = blockIdx.z;
    const int n0    = ntile * BN;

    __shared__ int   s_fwbuf[BATCH];
    __shared__ int   s_list[BATCH];
    __shared__ int   s_cnt;
    __shared__ short XT[BM][LDS_K];
    __shared__ short WT[BN][LDS_K];

    if (tid < BATCH) s_fwbuf[tid] = fwv[tid];
    __syncthreads();
    if (tid == 0) {
        int c = 0;
        for (int i = 0; i < BATCH; ++i)
            if (s_fwbuf[i] == myfw) s_list[c++] = i;
        s_cnt = c;
    }
    __syncthreads();
    const int cnt = s_cnt;
    if (mg * 4 >= cnt) return;               // uniform early-exit
    const int nvalid = min(4, cnt - mg * 4); // valid batch slots in this m-group

    // ---- staging thread maps ----
    // X: thread covers (row sm, k-half skb): 128 rows x 2 halves
    const int  sm    = tid >> 1;
    const int  skb   = (tid & 1) * 32;
    const int  sslot = sm >> 5;
    const bool svalid = (sslot < nvalid);
    const long sbatch = svalid ? s_list[mg * 4 + sslot] : 0;
    const float* xsrc = x + (sbatch * SEQ + (sm & 31)) * (long)DIM + skb;

    // W: thread covers (col wn, k-half wkb): 128 cols x 2 halves, column loads
    const int wn  = tid & 127;
    const int wkb = (tid >> 7) * 32;
    const float* wsrc = w + (long)myfw * DIM * EOUT + (long)wkb * EOUT + n0 + wn;

    // ---- wave / fragment geometry ----
    const int wave  = tid >> 6;
    const int lane  = tid & 63;
    const int wm    = (wave >> 1) * 64;   // wave row base in tile
    const int wncol = (wave & 1) * 64;    // wave col base in tile
    const int lrow  = lane & 15;
    const int lk    = (lane >> 4) * 4;    // per-lane k sub-offset

    f32x4 acc[4][4];
    #pragma unroll
    for (int i = 0; i < 4; ++i)
        #pragma unroll
        for (int j = 0; j < 4; ++j)
            acc[i][j] = (f32x4){0.f, 0.f, 0.f, 0.f};

    // zero-fill invalid X rows once (never overwritten later)
    if (!svalid) {
        s16x4 z = {0, 0, 0, 0};
        #pragma unroll
        for (int j = 0; j < 8; ++j) *(s16x4*)&XT[sm][skb + 4 * j] = z;
    }

    for (int k0 = 0; k0 < DIM; k0 += BK) {
        __syncthreads();   // previous compute done / zero-fill visible

        // stage X chunk: 8 x float4 -> bf16 -> 8 x ds_write_b64
        if (svalid) {
            const float* px = xsrc + k0;
            #pragma unroll
            for (int j = 0; j < 8; ++j) {
                float4 v = *(const float4*)(px + 4 * j);
                s16x4 p = { f2bf(v.x), f2bf(v.y), f2bf(v.z), f2bf(v.w) };
                *(s16x4*)&XT[sm][skb + 4 * j] = p;
            }
        }

        // stage W chunk transposed: 32 coalesced column dword loads -> [n][k]
        {
            const float* pw = wsrc + (long)k0 * EOUT;
            float wv[32];
            #pragma unroll
            for (int j = 0; j < 32; ++j) wv[j] = pw[(long)j * EOUT];
            #pragma unroll
            for (int j = 0; j < 8; ++j) {
                s16x4 p = { f2bf(wv[4*j]), f2bf(wv[4*j+1]),
                            f2bf(wv[4*j+2]), f2bf(wv[4*j+3]) };
                *(s16x4*)&WT[wn][wkb + 4 * j] = p;
            }
        }

        __syncthreads();   // staging visible

        #pragma unroll
        for (int kk = 0; kk < BK; kk += 32) {
            s16x8 a[4], b[4];
            #pragma unroll
            for (int i = 0; i < 4; ++i) {
                const short* p = &XT[wm + i * 16 + lrow][kk + lk];
                s16x4 lo = *(const s16x4*)p;
                s16x4 hi = *(const s16x4*)(p + 16);
                a[i] = __builtin_shufflevector(lo, hi, 0, 1, 2, 3, 4, 5, 6, 7);
            }
            #pragma unroll
            for (int i = 0; i < 4; ++i) {
                const short* p = &WT[wncol + i * 16 + lrow][kk + lk];
                s16x4 lo = *(const s16x4*)p;
                s16x4 hi = *(const s16x4*)(p + 16);
                b[i] = __builtin_shufflevector(lo, hi, 0, 1, 2, 3, 4, 5, 6, 7);
            }
            #pragma unroll
            for (int i = 0; i < 4; ++i)
                #pragma unroll
                for (int j = 0; j < 4; ++j)
                    acc[i][j] = __builtin_amdgcn_mfma_f32_16x16x32_bf16(
                        a[i], b[j], acc[i][j], 0, 0, 0);
        }
    }

    // ---- epilogue: +bias, tanh, store ----
    int bidx[4];
    #pragma unroll
    for (int s = 0; s < 4; ++s) bidx[s] = (s < nvalid) ? s_list[mg * 4 + s] : -1;
    const float* bv = bias + (long)myfw * EOUT;

    #pragma unroll
    for (int i = 0; i < 4; ++i) {
        const int mbase = wm + i * 16 + (lane >> 4) * 4;
        #pragma unroll
        for (int j = 0; j < 4; ++j) {
            const int col = n0 + wncol + j * 16 + lrow;
            const float bb = bv[col];
            #pragma unroll
            for (int r = 0; r < 4; ++r) {
                const int m    = mbase + r;
                const int slot = m >> 5;
                const int b    = bidx[slot];
                if (b >= 0) {
                    float v = acc[i][j][r] + bb;
                    float e = __expf(2.0f * v);
                    float t = 1.0f - __fdividef(2.0f, e + 1.0f);
                    out[((long)(b * SEQ + (m & 31))) * EOUT + col] = t;
                }
            }
        }
    }
}

extern "C" void kernel_launch(void* const* d_in, const int* in_sizes, int n_in,
                              void* d_out, int out_size, void* d_ws, size_t ws_size,
                              hipStream_t stream) {
    const float* x    = (const float*)d_in[0];
    const int*   fwv  = (const int*)d_in[1];
    const float* w    = (const float*)d_in[2];
    const float* bias = (const float*)d_in[3];
    float* out = (float*)d_out;

    dim3 grid(EOUT / BN, (BATCH + 3) / 4, NFW);   // (32, 16, 16)
    qgen_kernel<<<grid, 256, 0, stream>>>(x, fwv, w, bias, out);
}

// Round 2
// 121.237 us; speedup vs baseline: 1.1857x; 1.1857x over previous
//
#include <hip/hip_runtime.h>
#include <hip/hip_bf16.h>

#define BATCH 64
#define SEQ 32
#define DIM 1024
#define EOUT 4096
#define NFW 16

#define BM 128   // rows per block tile (4 batch-slots x 32 seq)
#define BN 128   // cols per block tile
#define BK 64    // k chunk
#define LDS_K 68 // padded row stride in bf16 elements (136B -> b64 reads 2-way only)

typedef float  f32x4 __attribute__((ext_vector_type(4)));
typedef short  s16x4 __attribute__((ext_vector_type(4)));
typedef short  s16x8 __attribute__((ext_vector_type(8)));

__device__ __forceinline__ short f2bf(float f) {
    union { float f; unsigned u; } v; v.f = f;
    unsigned r = v.u + 0x7fffu + ((v.u >> 16) & 1u);   // RNE
    return (short)(r >> 16);
}

__global__ __launch_bounds__(256) void qgen_kernel(
    const float* __restrict__ x,      // [64][32][1024]
    const int*   __restrict__ fwv,    // [64]
    const float* __restrict__ w,      // [16][1024][4096]
    const float* __restrict__ bias,   // [16][4096]
    float*       __restrict__ out)    // [64][32][4096] flat
{
    const int tid   = threadIdx.x;
    const int ntile = blockIdx.x;
    const int mg    = blockIdx.y;
    const int myfw  = blockIdx.z;
    const int n0    = ntile * BN;

    __shared__ int   s_list[BATCH];
    __shared__ int   s_cnt;
    __shared__ short XT[BM][LDS_K];
    __shared__ short WT[BN][LDS_K];

    // ---- W staging map (computed first so prologue loads issue ASAP) ----
    // thread covers (col wn, k-half wkb): 128 cols x 2 halves, column loads
    const int wn  = tid & 127;
    const int wkb = (tid >> 7) * 32;
    const float* wsrc = w + (long)myfw * DIM * EOUT + (long)wkb * EOUT + n0 + wn;

    // ---- prologue: issue W loads for chunk 0 immediately ----
    float wreg[32];
    #pragma unroll
    for (int j = 0; j < 32; ++j) wreg[j] = wsrc[(long)j * EOUT];

    // ---- wave-parallel framework scan (wave 0, ballot + rank) ----
    if (tid < 64) {
        const int myv = fwv[tid];
        const unsigned long long mask = __ballot(myv == myfw);
        if (myv == myfw) {
            const int rank = __popcll(mask & ((1ull << tid) - 1ull));
            s_list[rank] = tid;
        }
        if (tid == 0) s_cnt = __popcll(mask);
    }
    __syncthreads();
    const int cnt = s_cnt;
    if (mg * 4 >= cnt) return;               // uniform early-exit
    const int nvalid = min(4, cnt - mg * 4); // valid batch slots in this m-group

    // ---- X staging map ----
    // thread covers (row sm, k-half skb): 128 rows x 2 halves
    const int  sm    = tid >> 1;
    const int  skb   = (tid & 1) * 32;
    const int  sslot = sm >> 5;
    const bool svalid = (sslot < nvalid);
    const long sbatch = svalid ? s_list[mg * 4 + sslot] : 0;
    const float* xsrc = x + (sbatch * SEQ + (sm & 31)) * (long)DIM + skb;

    // ---- wave / fragment geometry ----
    const int wave  = tid >> 6;
    const int lane  = tid & 63;
    const int wm    = (wave >> 1) * 64;   // wave row base in tile
    const int wncol = (wave & 1) * 64;    // wave col base in tile
    const int lrow  = lane & 15;
    const int lk    = (lane >> 4) * 4;    // per-lane k sub-offset

    f32x4 acc[4][4];
    #pragma unroll
    for (int i = 0; i < 4; ++i)
        #pragma unroll
        for (int j = 0; j < 4; ++j)
            acc[i][j] = (f32x4){0.f, 0.f, 0.f, 0.f};

    // zero-fill invalid X rows once (never overwritten later)
    if (!svalid) {
        s16x4 z = {0, 0, 0, 0};
        #pragma unroll
        for (int j = 0; j < 8; ++j) *(s16x4*)&XT[sm][skb + 4 * j] = z;
    }

    for (int k0 = 0; k0 < DIM; k0 += BK) {
        __syncthreads();   // previous compute done reading LDS / zero-fill visible

        // (1) issue X loads early — latency overlaps W cvt+write below
        float4 xv[8];
        if (svalid) {
            const float* px = xsrc + k0;
            #pragma unroll
            for (int j = 0; j < 8; ++j) xv[j] = *(const float4*)(px + 4 * j);
        }

        // (2) W: cvt + ds_write (wreg landed during previous MFMA phase)
        #pragma unroll
        for (int j = 0; j < 8; ++j) {
            s16x4 p = { f2bf(wreg[4*j]), f2bf(wreg[4*j+1]),
                        f2bf(wreg[4*j+2]), f2bf(wreg[4*j+3]) };
            *(s16x4*)&WT[wn][wkb + 4 * j] = p;
        }

        // (3) issue W loads for next chunk (in flight across MFMA phase)
        {
            const long k1 = (k0 + BK < DIM) ? (long)(k0 + BK) : 0;
            const float* pw = wsrc + k1 * EOUT;
            #pragma unroll
            for (int j = 0; j < 32; ++j) wreg[j] = pw[(long)j * EOUT];
        }

        // (4) X: cvt + ds_write
        if (svalid) {
            #pragma unroll
            for (int j = 0; j < 8; ++j) {
                s16x4 p = { f2bf(xv[j].x), f2bf(xv[j].y),
                            f2bf(xv[j].z), f2bf(xv[j].w) };
                *(s16x4*)&XT[sm][skb + 4 * j] = p;
            }
        }

        __syncthreads();   // staging visible

        #pragma unroll
        for (int kk = 0; kk < BK; kk += 32) {
            s16x8 a[4], b[4];
            #pragma unroll
            for (int i = 0; i < 4; ++i) {
                const short* p = &XT[wm + i * 16 + lrow][kk + lk];
                s16x4 lo = *(const s16x4*)p;
                s16x4 hi = *(const s16x4*)(p + 16);
                a[i] = __builtin_shufflevector(lo, hi, 0, 1, 2, 3, 4, 5, 6, 7);
            }
            #pragma unroll
            for (int i = 0; i < 4; ++i) {
                const short* p = &WT[wncol + i * 16 + lrow][kk + lk];
                s16x4 lo = *(const s16x4*)p;
                s16x4 hi = *(const s16x4*)(p + 16);
                b[i] = __builtin_shufflevector(lo, hi, 0, 1, 2, 3, 4, 5, 6, 7);
            }
            #pragma unroll
            for (int i = 0; i < 4; ++i)
                #pragma unroll
                for (int j = 0; j < 4; ++j)
                    acc[i][j] = __builtin_amdgcn_mfma_f32_16x16x32_bf16(
                        a[i], b[j], acc[i][j], 0, 0, 0);
        }
    }

    // ---- epilogue: +bias, tanh, store ----
    int bidx[4];
    #pragma unroll
    for (int s = 0; s < 4; ++s) bidx[s] = (s < nvalid) ? s_list[mg * 4 + s] : -1;
    const float* bv = bias + (long)myfw * EOUT;

    #pragma unroll
    for (int i = 0; i < 4; ++i) {
        const int mbase = wm + i * 16 + (lane >> 4) * 4;
        #pragma unroll
        for (int j = 0; j < 4; ++j) {
            const int col = n0 + wncol + j * 16 + lrow;
            const float bb = bv[col];
            #pragma unroll
            for (int r = 0; r < 4; ++r) {
                const int m    = mbase + r;
                const int slot = m >> 5;
                const int b    = bidx[slot];
                if (b >= 0) {
                    float v = acc[i][j][r] + bb;
                    float e = __expf(2.0f * v);
                    float t = 1.0f - __fdividef(2.0f, e + 1.0f);
                    out[((long)(b * SEQ + (m & 31))) * EOUT + col] = t;
                }
            }
        }
    }
}

extern "C" void kernel_launch(void* const* d_in, const int* in_sizes, int n_in,
                              void* d_out, int out_size, void* d_ws, size_t ws_size,
                              hipStream_t stream) {
    const float* x    = (const float*)d_in[0];
    const int*   fwv  = (const int*)d_in[1];
    const float* w    = (const float*)d_in[2];
    const float* bias = (const float*)d_in[3];
    float* out = (float*)d_out;

    dim3 grid(EOUT / BN, (BATCH + 3) / 4, NFW);   // (32, 16, 16)
    qgen_kernel<<<grid, 256, 0, stream>>>(x, fwv, w, bias, out);
}